// Round 16
// baseline (312.691 us; speedup 1.0000x reference)
//
#include <hip/hip_runtime.h>
#include <cstdint>
#include <cstddef>

typedef unsigned short u16;
typedef __attribute__((ext_vector_type(4)))  u16    u16x4;
typedef __attribute__((ext_vector_type(8)))  u16    u16x8;
typedef __attribute__((ext_vector_type(8)))  __bf16 bf16x8;
typedef __attribute__((ext_vector_type(4)))  float  f32x4;
typedef __attribute__((ext_vector_type(16))) float  f32x16;

#define BB 2
#define SS 2048
#define DD 1024
#define HH 16
#define HDD 64
// log2(e)/sqrt(HD): folded into Q and rel_bias so attn does exp2(a + b) only
#define QSCL 0.18033688011112042f

__device__ __forceinline__ u16 f2bf(float f) {
  unsigned u = __builtin_bit_cast(unsigned, f);
  u += 0x7FFFu + ((u >> 16) & 1u);
  return (u16)(u >> 16);
}

__device__ __forceinline__ f32x16 mfma32(u16x8 a, u16x8 b, f32x16 c) {
  return __builtin_amdgcn_mfma_f32_32x32x16_bf16(
      __builtin_bit_cast(bf16x8, a), __builtin_bit_cast(bf16x8, b), c, 0, 0, 0);
}
__device__ __forceinline__ f32x4 mfma16(u16x8 a, u16x8 b, f32x4 c) {
  return __builtin_amdgcn_mfma_f32_16x16x32_bf16(
      __builtin_bit_cast(bf16x8, a), __builtin_bit_cast(bf16x8, b), c, 0, 0, 0);
}

// async global->LDS, 16B per lane; LDS dest = wave-uniform base + lane*16
__device__ __forceinline__ void gload16(const u16* g, u16* l) {
  typedef const __attribute__((address_space(1))) unsigned GQ;
  typedef __attribute__((address_space(3))) unsigned LQ;
  __builtin_amdgcn_global_load_lds((GQ*)(uintptr_t)g, (LQ*)(uint32_t)(uintptr_t)l,
                                   16, 0, 0);
}

// ---------------- kernel 1: fp32 -> bf16 conversion/packing ----------------
__global__ __launch_bounds__(256) void mhsa_convert(
    const float* __restrict__ x, const float* __restrict__ wq,
    const float* __restrict__ wk, const float* __restrict__ wv,
    const float* __restrict__ wo,
    u16* __restrict__ xb, u16* __restrict__ wpack, u16* __restrict__ wob) {
  const size_t NX = (size_t)BB * SS * DD;      // 4194304
  const size_t NW = (size_t)DD * DD;           // 1048576
  const size_t nch = (NX + 4 * NW) >> 2;
  for (size_t i = (size_t)blockIdx.x * 256 + threadIdx.x; i < nch;
       i += (size_t)gridDim.x * 256) {
    size_t e = i << 2;
    const float* s; u16* d;
    if (e < NX)               { s = x  + e;                d = xb + e; }
    else if (e < NX + NW)     { s = wq + (e - NX);         d = wpack + (e - NX); }
    else if (e < NX + 2 * NW) { s = wk + (e - NX - NW);    d = wpack + (e - NX); }
    else if (e < NX + 3 * NW) { s = wv + (e - NX - 2*NW);  d = wpack + (e - NX); }
    else                      { s = wo + (e - NX - 3*NW);  d = wob + (e - NX - 3*NW); }
    f32x4 v = *(const f32x4*)s;
    u16x4 o; o[0] = f2bf(v[0]); o[1] = f2bf(v[1]); o[2] = f2bf(v[2]); o[3] = f2bf(v[3]);
    *(u16x4*)d = o;
  }
}

// ---------------- kernel 2: QKV projection GEMM (128x128, m97) -------------
// C[4096,3072] = xb * wpack^T; grid (24 bn, 32 bm). Q pre-scaled by QSCL.
// Epilogue stages the C tile in LDS (padded stride 136) then stores u16x8
// coalesced (R10-measured best).
__global__ __launch_bounds__(256) void mhsa_gemm_qkv(
    const u16* __restrict__ A, const u16* __restrict__ Bm,
    const float* __restrict__ bq, const float* __restrict__ bk,
    const float* __restrict__ bv,
    u16* __restrict__ Q, u16* __restrict__ K, u16* __restrict__ V) {
  const int KD = DD;
  __shared__ __attribute__((aligned(16))) u16 smem[128 * 136];
  u16* lA = smem;           // 128*64
  u16* lB = smem + 8192;    // 128*64
  int tid = threadIdx.x;
  int bm = blockIdx.y, bn = blockIdx.x;
  int l = tid & 63, w = tid >> 6, wr = w >> 1, wc = w & 1;
  int l15 = l & 15, l4 = l >> 4;
  f32x4 acc[4][4];
#pragma unroll
  for (int mi = 0; mi < 4; mi++)
#pragma unroll
    for (int ni = 0; ni < 4; ni++)
#pragma unroll
      for (int j = 0; j < 4; j++) acc[mi][ni][j] = 0.f;

  const u16* Ag = A + (size_t)bm * 128 * KD;
  const u16* Bg = Bm + (size_t)bn * 128 * KD;
  const int srow = (l >> 3), scol = (l & 7) * 8;
  for (int kt = 0; kt < KD / 64; kt++) {
    const u16* As = Ag + (size_t)(w * 32 + srow) * KD + kt * 64 + scol;
    const u16* Bs = Bg + (size_t)(w * 32 + srow) * KD + kt * 64 + scol;
    u16* Ad = &lA[(w * 32) * 64];
    u16* Bd = &lB[(w * 32) * 64];
#pragma unroll
    for (int t = 0; t < 4; t++) {
      gload16(As + (size_t)t * 8 * KD, Ad + t * 8 * 64);
      gload16(Bs + (size_t)t * 8 * KD, Bd + t * 8 * 64);
    }
    __syncthreads();
#pragma unroll
    for (int kk = 0; kk < 64; kk += 32) {
      u16x8 af[4], bf[4];
#pragma unroll
      for (int mi = 0; mi < 4; mi++)
        af[mi] = *(const u16x8*)&lA[(wr * 64 + mi * 16 + l15) * 64 + kk + l4 * 8];
#pragma unroll
      for (int ni = 0; ni < 4; ni++)
        bf[ni] = *(const u16x8*)&lB[(wc * 64 + ni * 16 + l15) * 64 + kk + l4 * 8];
#pragma unroll
      for (int mi = 0; mi < 4; mi++)
#pragma unroll
        for (int ni = 0; ni < 4; ni++)
          acc[mi][ni] = mfma16(af[mi], bf[ni], acc[mi][ni]);
    }
    __syncthreads();
  }
  // ---- epilogue: bias+scale -> LDS tile -> coalesced u16x8 stores ----
  const int which = (bn * 128) >> 10;
  const float* bp = (which == 0) ? bq : (which == 1) ? bk : bv;
  u16* dst = (which == 0) ? Q : (which == 1) ? K : V;
  const float scl = (which == 0) ? QSCL : 1.0f;
#pragma unroll
  for (int ni = 0; ni < 4; ni++) {
    int col = bn * 128 + wc * 64 + ni * 16 + l15;
    float bias = bp[col & 1023];
    int lc = wc * 64 + ni * 16 + l15;
#pragma unroll
    for (int mi = 0; mi < 4; mi++) {
#pragma unroll
      for (int j = 0; j < 4; j++) {
        int lr = wr * 64 + mi * 16 + l4 * 4 + j;
        smem[lr * 136 + lc] = f2bf((acc[mi][ni][j] + bias) * scl);
      }
    }
  }
  __syncthreads();
#pragma unroll
  for (int t = 0; t < 8; t++) {
    int idx = tid + t * 256;
    int row = idx >> 4, c8 = idx & 15;
    u16x8 v = *(const u16x8*)&smem[row * 136 + c8 * 8];
    int sg = bm * 128 + row;
    int b = sg >> 11, s = sg & 2047;
    int cc = (bn * 128 + c8 * 8) & 1023;
    int h = cc >> 6, hd = cc & 63;
    *(u16x8*)&dst[(((size_t)b * HH + h) * SS + s) * HDD + hd] = v;
  }
}

// ---------------- kernel 3: V -> V^T  ([bh][s][hd] -> [bh][hd][s]) ----------
__global__ __launch_bounds__(256) void mhsa_transpose_v(
    const u16* __restrict__ Vb, u16* __restrict__ Vt) {
  __shared__ u16 t[64][72];
  int st = blockIdx.x, bh = blockIdx.y;
  int tid = threadIdx.x;
  int r = tid >> 2, c0 = (tid & 3) * 16;
  const u16* src = Vb + ((size_t)bh * SS + st * 64) * HDD;
  u16x8 v0 = *(const u16x8*)&src[r * 64 + c0];
  u16x8 v1 = *(const u16x8*)&src[r * 64 + c0 + 8];
#pragma unroll
  for (int j = 0; j < 8; j++) { t[r][c0 + j] = v0[j]; t[r][c0 + 8 + j] = v1[j]; }
  __syncthreads();
  u16* dst = Vt + ((size_t)bh * HDD + r) * SS + st * 64 + c0;
  u16x8 o0, o1;
#pragma unroll
  for (int j = 0; j < 8; j++) { o0[j] = t[c0 + j][r]; o1[j] = t[c0 + 8 + j][r]; }
  *(u16x8*)&dst[0] = o0;
  *(u16x8*)&dst[8] = o1;
}

// ---------------- kernel 4: fused scores+bias+exp(no-max)+softmax+PV -------
// grid (64 qb, 32 bh). Weight stores moved to a TAIL loop after the last
// barrier: the S4 __syncthreads no longer forces a vmcnt(0) drain of the
// 256KB/block store burst; drain overlaps the next block's QK phase.
__global__ __launch_bounds__(512, 2) void mhsa_attn(
    const u16* __restrict__ Qb, const u16* __restrict__ Kb,
    const u16* __restrict__ Vt, const float* __restrict__ rel_bias,
    float* __restrict__ wout, u16* __restrict__ attn) {
  int qb = blockIdx.x, bh = blockIdx.y;
  int h = bh & (HH - 1);
  int q0 = qb * 32;
  int tid = threadIdx.x;
  int w = tid >> 6, l = tid & 63, l31 = l & 31, hi = l >> 5;

  __shared__ float bias_lds[2080];
  __shared__ float red[8][32];
  __shared__ float gval[32];
  __shared__ __attribute__((aligned(16))) u16 plds[8][32][40];
  __shared__ float pvred[4][32][64];

  for (int i = tid; i < 2079; i += 512)
    bias_lds[i] = rel_bias[(size_t)(q0 + i) * HH + h] * QSCL;

  const u16* Qp = Qb + ((size_t)bh * SS + q0) * HDD;
  u16x8 aq[4];
#pragma unroll
  for (int c = 0; c < 4; c++)
    aq[c] = *(const u16x8*)&Qp[l31 * 64 + c * 16 + hi * 8];

  __syncthreads();  // S1: bias staged

  int rowq[16];
#pragma unroll
  for (int r = 0; r < 16; r++) rowq[r] = (r & 3) + 8 * (r >> 2) + 4 * hi;

  // -------- fused: scores = QK^T (pre-scaled), +bias, exp2, row-sum --------
  const u16* Kp = Kb + (size_t)bh * SS * HDD;
  f32x16 acc[8];
  float s16[16];
#pragma unroll
  for (int r = 0; r < 16; r++) s16[r] = 0.f;
#pragma unroll
  for (int kt = 0; kt < 8; kt++) {
    int kg = w * 256 + kt * 32;
    f32x16 a;
#pragma unroll
    for (int j = 0; j < 16; j++) a[j] = 0.f;
#pragma unroll
    for (int c = 0; c < 4; c++) {
      u16x8 kf = *(const u16x8*)&Kp[(size_t)(kg + l31) * 64 + c * 16 + hi * 8];
      a = mfma32(aq[c], kf, a);
    }
    int kgl = kg + l31;
#pragma unroll
    for (int r = 0; r < 16; r++) {
      float p = exp2f(a[r] + bias_lds[rowq[r] + 2047 - kgl]);
      a[r] = p;
      s16[r] += p;
    }
    acc[kt] = a;
  }
  // -------- cross-lane + cross-wave row sum --------
#pragma unroll
  for (int mask = 1; mask <= 16; mask <<= 1)
#pragma unroll
    for (int r = 0; r < 16; r++) s16[r] += __shfl_xor(s16[r], mask);
  if (l31 == 0) {
#pragma unroll
    for (int r = 0; r < 16; r++) red[w][rowq[r]] = s16[r];
  }
  __syncthreads();  // S2
  if (tid < 32) {
    float g = 0.f;
#pragma unroll
    for (int ww = 0; ww < 8; ww++) g += red[ww][tid];
    gval[tid] = g;
  }
  __syncthreads();  // S3
  float inv16[16];
#pragma unroll
  for (int r = 0; r < 16; r++) inv16[r] = 1.0f / gval[rowq[r]];

  // -------- PV (no weight stores here; acc keeps unnormalized p) --------
  const u16* Vp = Vt + (size_t)bh * HDD * SS;
  f32x16 pv0, pv1;
#pragma unroll
  for (int j = 0; j < 16; j++) { pv0[j] = 0.f; pv1[j] = 0.f; }

#pragma unroll
  for (int kt = 0; kt < 8; kt++) {
    int kg = w * 256 + kt * 32;
#pragma unroll
    for (int r = 0; r < 16; r++) {
      float wv = acc[kt][r] * inv16[r];
      plds[w][rowq[r]][l31] = f2bf(wv);
    }
#pragma unroll
    for (int kk = 0; kk < 32; kk += 16) {
      u16x8 pa  = *(const u16x8*)&plds[w][l31][kk + hi * 8];
      u16x8 vb0 = *(const u16x8*)&Vp[(size_t)l31 * SS + kg + kk + hi * 8];
      u16x8 vb1 = *(const u16x8*)&Vp[(size_t)(32 + l31) * SS + kg + kk + hi * 8];
      pv0 = mfma32(pa, vb0, pv0);
      pv1 = mfma32(pa, vb1, pv1);
    }
  }
  // -------- cross-wave PV reduction --------
  if (w >= 4) {
#pragma unroll
    for (int r = 0; r < 16; r++) {
      pvred[w - 4][rowq[r]][l31]      = pv0[r];
      pvred[w - 4][rowq[r]][32 + l31] = pv1[r];
    }
  }
  __syncthreads();  // S4
  if (w < 4) {
#pragma unroll
    for (int r = 0; r < 16; r++) {
      pvred[w][rowq[r]][l31]      += pv0[r];
      pvred[w][rowq[r]][32 + l31] += pv1[r];
    }
  }
  __syncthreads();  // S5 (last barrier)
  int b = bh >> 4;
  for (int idx = tid; idx < 2048; idx += 512) {
    int qq = idx >> 6, hd = idx & 63;
    float sum = 0.f;
#pragma unroll
    for (int ww = 0; ww < 4; ww++) sum += pvred[ww][qq][hd];
    attn[((size_t)b * SS + q0 + qq) * DD + h * HDD + hd] = f2bf(sum);
  }
  // -------- tail: weight stores (no barrier after; drain overlaps) --------
  float* wbase = wout + ((size_t)bh * SS + q0) * (size_t)SS;
#pragma unroll
  for (int kt = 0; kt < 8; kt++) {
    int kg = w * 256 + kt * 32;
#pragma unroll
    for (int r = 0; r < 16; r++)
      __builtin_nontemporal_store(acc[kt][r] * inv16[r],
                                  &wbase[(size_t)rowq[r] * SS + kg + l31]);
  }
}

// ---------------- kernel 5: output projection GEMM (m97 structure) ---------
__global__ __launch_bounds__(256) void mhsa_gemm_out(
    const u16* __restrict__ A, const u16* __restrict__ Bm,
    const float* __restrict__ bo, float* __restrict__ out) {
  const int KD = DD;
  __shared__ __attribute__((aligned(16))) u16 lA[128 * 64];
  __shared__ __attribute__((aligned(16))) u16 lB[64 * 64];
  int tid = threadIdx.x;
  int bm = blockIdx.y, bn = blockIdx.x;
  int l = tid & 63, w = tid >> 6, wr = w >> 1, wc = w & 1;
  int l15 = l & 15, l4 = l >> 4;
  f32x4 acc[4][2];
#pragma unroll
  for (int mi = 0; mi < 4; mi++)
#pragma unroll
    for (int ni = 0; ni < 2; ni++)
#pragma unroll
      for (int j = 0; j < 4; j++) acc[mi][ni][j] = 0.f;

  const u16* Ag = A + (size_t)bm * 128 * KD;
  const u16* Bg = Bm + (size_t)bn * 64 * KD;
  const int srow = (l >> 3), scol = (l & 7) * 8;
  for (int kt = 0; kt < KD / 64; kt++) {
    const u16* As = Ag + (size_t)(w * 32 + srow) * KD + kt * 64 + scol;
    const u16* Bs = Bg + (size_t)(w * 16 + srow) * KD + kt * 64 + scol;
    u16* Ad = &lA[(w * 32) * 64];
    u16* Bd = &lB[(w * 16) * 64];
#pragma unroll
    for (int t = 0; t < 4; t++)
      gload16(As + (size_t)t * 8 * KD, Ad + t * 8 * 64);
#pragma unroll
    for (int t = 0; t < 2; t++)
      gload16(Bs + (size_t)t * 8 * KD, Bd + t * 8 * 64);
    __syncthreads();
#pragma unroll
    for (int kk = 0; kk < 64; kk += 32) {
      u16x8 af[4], bf[2];
#pragma unroll
      for (int mi = 0; mi < 4; mi++)
        af[mi] = *(const u16x8*)&lA[(wr * 64 + mi * 16 + l15) * 64 + kk + l4 * 8];
#pragma unroll
      for (int ni = 0; ni < 2; ni++)
        bf[ni] = *(const u16x8*)&lB[(wc * 32 + ni * 16 + l15) * 64 + kk + l4 * 8];
#pragma unroll
      for (int mi = 0; mi < 4; mi++)
#pragma unroll
        for (int ni = 0; ni < 2; ni++)
          acc[mi][ni] = mfma16(af[mi], bf[ni], acc[mi][ni]);
    }
    __syncthreads();
  }
  int rowbase = bm * 128 + wr * 64;
  int colbase = bn * 64 + wc * 32;
#pragma unroll
  for (int ni = 0; ni < 2; ni++) {
    int col = colbase + ni * 16 + l15;
    float bias = bo[col];
#pragma unroll
    for (int mi = 0; mi < 4; mi++) {
#pragma unroll
      for (int j = 0; j < 4; j++) {
        int row = rowbase + mi * 16 + l4 * 4 + j;
        out[(size_t)row * DD + col] = acc[mi][ni][j] + bias;
      }
    }
  }
}

// ---------------- launcher -------------------------------------------------
extern "C" void kernel_launch(void* const* d_in, const int* in_sizes, int n_in,
                              void* d_out, int out_size, void* d_ws, size_t ws_size,
                              hipStream_t stream) {
  const float* x  = (const float*)d_in[0];
  const float* Wq = (const float*)d_in[1];
  const float* bq = (const float*)d_in[2];
  const float* Wk = (const float*)d_in[3];
  const float* bk = (const float*)d_in[4];
  const float* Wv = (const float*)d_in[5];
  const float* bv = (const float*)d_in[6];
  const float* Wo = (const float*)d_in[7];
  const float* bo = (const float*)d_in[8];
  const float* rb = (const float*)d_in[9];

  char* ws = (char*)d_ws;
  u16* xb    = (u16*)(ws + 0);           //  8 MiB  (4096x1024)
  u16* wpack = (u16*)(ws + 8388608);     //  6 MiB  (3072x1024)
  u16* wob   = (u16*)(ws + 14680064);    //  2 MiB  (1024x1024)
  u16* Qb    = (u16*)(ws + 16777216);    //  8 MiB  [b,h,s,hd] (pre-scaled)
  u16* Kb    = (u16*)(ws + 25165824);    //  8 MiB
  u16* Vb    = (u16*)(ws + 33554432);    //  8 MiB
  u16* Vt    = (u16*)(ws + 41943040);    //  8 MiB  [b,h,hd,s]
  u16* attnb = (u16*)(ws + 50331648);    //  8 MiB  [b,s,h*hd]
  if (ws_size < 58720256) return;

  float* out   = (float*)d_out;
  float* wout  = out + (size_t)BB * SS * DD;  // weights region

  mhsa_convert<<<2048, 256, 0, stream>>>(x, Wq, Wk, Wv, Wo, xb, wpack, wob);
  mhsa_gemm_qkv<<<dim3(24, 32), 256, 0, stream>>>(xb, wpack, bq, bk, bv, Qb, Kb, Vb);
  mhsa_transpose_v<<<dim3(32, 32), 256, 0, stream>>>(Vb, Vt);
  mhsa_attn<<<dim3(64, 32), 512, 0, stream>>>(Qb, Kb, Vt, rb, wout, attnb);
  mhsa_gemm_out<<<dim3(16, 32), 256, 0, stream>>>(attnb, wob, bo, out);
}

// Round 17
// 276.742 us; speedup vs baseline: 1.1299x; 1.1299x over previous
//
#include <hip/hip_runtime.h>
#include <cstdint>
#include <cstddef>

typedef unsigned short u16;
typedef __attribute__((ext_vector_type(4)))  u16    u16x4;
typedef __attribute__((ext_vector_type(8)))  u16    u16x8;
typedef __attribute__((ext_vector_type(8)))  __bf16 bf16x8;
typedef __attribute__((ext_vector_type(4)))  float  f32x4;
typedef __attribute__((ext_vector_type(16))) float  f32x16;

#define BB 2
#define SS 2048
#define DD 1024
#define HH 16
#define HDD 64
// log2(e)/sqrt(HD): folded into Q and rel_bias so attn does exp2(a + b) only
#define QSCL 0.18033688011112042f

__device__ __forceinline__ u16 f2bf(float f) {
  unsigned u = __builtin_bit_cast(unsigned, f);
  u += 0x7FFFu + ((u >> 16) & 1u);
  return (u16)(u >> 16);
}

__device__ __forceinline__ f32x16 mfma32(u16x8 a, u16x8 b, f32x16 c) {
  return __builtin_amdgcn_mfma_f32_32x32x16_bf16(
      __builtin_bit_cast(bf16x8, a), __builtin_bit_cast(bf16x8, b), c, 0, 0, 0);
}
__device__ __forceinline__ f32x4 mfma16(u16x8 a, u16x8 b, f32x4 c) {
  return __builtin_amdgcn_mfma_f32_16x16x32_bf16(
      __builtin_bit_cast(bf16x8, a), __builtin_bit_cast(bf16x8, b), c, 0, 0, 0);
}

// async global->LDS, 16B per lane; LDS dest = wave-uniform base + lane*16
__device__ __forceinline__ void gload16(const u16* g, u16* l) {
  typedef const __attribute__((address_space(1))) unsigned GQ;
  typedef __attribute__((address_space(3))) unsigned LQ;
  __builtin_amdgcn_global_load_lds((GQ*)(uintptr_t)g, (LQ*)(uint32_t)(uintptr_t)l,
                                   16, 0, 0);
}

// ---------------- kernel 1: fp32 -> bf16 conversion/packing ----------------
__global__ __launch_bounds__(256) void mhsa_convert(
    const float* __restrict__ x, const float* __restrict__ wq,
    const float* __restrict__ wk, const float* __restrict__ wv,
    const float* __restrict__ wo,
    u16* __restrict__ xb, u16* __restrict__ wpack, u16* __restrict__ wob) {
  const size_t NX = (size_t)BB * SS * DD;      // 4194304
  const size_t NW = (size_t)DD * DD;           // 1048576
  const size_t nch = (NX + 4 * NW) >> 2;
  for (size_t i = (size_t)blockIdx.x * 256 + threadIdx.x; i < nch;
       i += (size_t)gridDim.x * 256) {
    size_t e = i << 2;
    const float* s; u16* d;
    if (e < NX)               { s = x  + e;                d = xb + e; }
    else if (e < NX + NW)     { s = wq + (e - NX);         d = wpack + (e - NX); }
    else if (e < NX + 2 * NW) { s = wk + (e - NX - NW);    d = wpack + (e - NX); }
    else if (e < NX + 3 * NW) { s = wv + (e - NX - 2*NW);  d = wpack + (e - NX); }
    else                      { s = wo + (e - NX - 3*NW);  d = wob + (e - NX - 3*NW); }
    f32x4 v = *(const f32x4*)s;
    u16x4 o; o[0] = f2bf(v[0]); o[1] = f2bf(v[1]); o[2] = f2bf(v[2]); o[3] = f2bf(v[3]);
    *(u16x4*)d = o;
  }
}

// ---------------- kernel 2: QKV projection GEMM (128x128, m97) -------------
// C[4096,3072] = xb * wpack^T; grid (24 bn, 32 bm). Q pre-scaled by QSCL.
// Epilogue stages the C tile in LDS (padded stride 136) then stores u16x8
// coalesced (R10-measured best).
__global__ __launch_bounds__(256) void mhsa_gemm_qkv(
    const u16* __restrict__ A, const u16* __restrict__ Bm,
    const float* __restrict__ bq, const float* __restrict__ bk,
    const float* __restrict__ bv,
    u16* __restrict__ Q, u16* __restrict__ K, u16* __restrict__ V) {
  const int KD = DD;
  __shared__ __attribute__((aligned(16))) u16 smem[128 * 136];
  u16* lA = smem;           // 128*64
  u16* lB = smem + 8192;    // 128*64
  int tid = threadIdx.x;
  int bm = blockIdx.y, bn = blockIdx.x;
  int l = tid & 63, w = tid >> 6, wr = w >> 1, wc = w & 1;
  int l15 = l & 15, l4 = l >> 4;
  f32x4 acc[4][4];
#pragma unroll
  for (int mi = 0; mi < 4; mi++)
#pragma unroll
    for (int ni = 0; ni < 4; ni++)
#pragma unroll
      for (int j = 0; j < 4; j++) acc[mi][ni][j] = 0.f;

  const u16* Ag = A + (size_t)bm * 128 * KD;
  const u16* Bg = Bm + (size_t)bn * 128 * KD;
  const int srow = (l >> 3), scol = (l & 7) * 8;
  for (int kt = 0; kt < KD / 64; kt++) {
    const u16* As = Ag + (size_t)(w * 32 + srow) * KD + kt * 64 + scol;
    const u16* Bs = Bg + (size_t)(w * 32 + srow) * KD + kt * 64 + scol;
    u16* Ad = &lA[(w * 32) * 64];
    u16* Bd = &lB[(w * 32) * 64];
#pragma unroll
    for (int t = 0; t < 4; t++) {
      gload16(As + (size_t)t * 8 * KD, Ad + t * 8 * 64);
      gload16(Bs + (size_t)t * 8 * KD, Bd + t * 8 * 64);
    }
    __syncthreads();
#pragma unroll
    for (int kk = 0; kk < 64; kk += 32) {
      u16x8 af[4], bf[4];
#pragma unroll
      for (int mi = 0; mi < 4; mi++)
        af[mi] = *(const u16x8*)&lA[(wr * 64 + mi * 16 + l15) * 64 + kk + l4 * 8];
#pragma unroll
      for (int ni = 0; ni < 4; ni++)
        bf[ni] = *(const u16x8*)&lB[(wc * 64 + ni * 16 + l15) * 64 + kk + l4 * 8];
#pragma unroll
      for (int mi = 0; mi < 4; mi++)
#pragma unroll
        for (int ni = 0; ni < 4; ni++)
          acc[mi][ni] = mfma16(af[mi], bf[ni], acc[mi][ni]);
    }
    __syncthreads();
  }
  // ---- epilogue: bias+scale -> LDS tile -> coalesced u16x8 stores ----
  const int which = (bn * 128) >> 10;
  const float* bp = (which == 0) ? bq : (which == 1) ? bk : bv;
  u16* dst = (which == 0) ? Q : (which == 1) ? K : V;
  const float scl = (which == 0) ? QSCL : 1.0f;
#pragma unroll
  for (int ni = 0; ni < 4; ni++) {
    int col = bn * 128 + wc * 64 + ni * 16 + l15;
    float bias = bp[col & 1023];
    int lc = wc * 64 + ni * 16 + l15;
#pragma unroll
    for (int mi = 0; mi < 4; mi++) {
#pragma unroll
      for (int j = 0; j < 4; j++) {
        int lr = wr * 64 + mi * 16 + l4 * 4 + j;
        smem[lr * 136 + lc] = f2bf((acc[mi][ni][j] + bias) * scl);
      }
    }
  }
  __syncthreads();
#pragma unroll
  for (int t = 0; t < 8; t++) {
    int idx = tid + t * 256;
    int row = idx >> 4, c8 = idx & 15;
    u16x8 v = *(const u16x8*)&smem[row * 136 + c8 * 8];
    int sg = bm * 128 + row;
    int b = sg >> 11, s = sg & 2047;
    int cc = (bn * 128 + c8 * 8) & 1023;
    int h = cc >> 6, hd = cc & 63;
    *(u16x8*)&dst[(((size_t)b * HH + h) * SS + s) * HDD + hd] = v;
  }
}

// ---------------- kernel 3: V -> V^T  ([bh][s][hd] -> [bh][hd][s]) ----------
__global__ __launch_bounds__(256) void mhsa_transpose_v(
    const u16* __restrict__ Vb, u16* __restrict__ Vt) {
  __shared__ u16 t[64][72];
  int st = blockIdx.x, bh = blockIdx.y;
  int tid = threadIdx.x;
  int r = tid >> 2, c0 = (tid & 3) * 16;
  const u16* src = Vb + ((size_t)bh * SS + st * 64) * HDD;
  u16x8 v0 = *(const u16x8*)&src[r * 64 + c0];
  u16x8 v1 = *(const u16x8*)&src[r * 64 + c0 + 8];
#pragma unroll
  for (int j = 0; j < 8; j++) { t[r][c0 + j] = v0[j]; t[r][c0 + 8 + j] = v1[j]; }
  __syncthreads();
  u16* dst = Vt + ((size_t)bh * HDD + r) * SS + st * 64 + c0;
  u16x8 o0, o1;
#pragma unroll
  for (int j = 0; j < 8; j++) { o0[j] = t[c0 + j][r]; o1[j] = t[c0 + 8 + j][r]; }
  *(u16x8*)&dst[0] = o0;
  *(u16x8*)&dst[8] = o1;
}

// ---------------- kernel 4: fused scores+bias+exp(no-max)+softmax+PV -------
// grid (64 qb, 32 bh). Q and bias pre-scaled by QSCL -> inner op: exp2(a+b).
// Weight stores interleaved in the PV loop (R10-measured best overlap).
__global__ __launch_bounds__(512, 2) void mhsa_attn(
    const u16* __restrict__ Qb, const u16* __restrict__ Kb,
    const u16* __restrict__ Vt, const float* __restrict__ rel_bias,
    float* __restrict__ wout, u16* __restrict__ attn) {
  int qb = blockIdx.x, bh = blockIdx.y;
  int h = bh & (HH - 1);
  int q0 = qb * 32;
  int tid = threadIdx.x;
  int w = tid >> 6, l = tid & 63, l31 = l & 31, hi = l >> 5;

  __shared__ float bias_lds[2080];
  __shared__ float red[8][32];
  __shared__ float gval[32];
  __shared__ __attribute__((aligned(16))) u16 plds[8][32][40];
  __shared__ float pvred[4][32][64];

  for (int i = tid; i < 2079; i += 512)
    bias_lds[i] = rel_bias[(size_t)(q0 + i) * HH + h] * QSCL;

  const u16* Qp = Qb + ((size_t)bh * SS + q0) * HDD;
  u16x8 aq[4];
#pragma unroll
  for (int c = 0; c < 4; c++)
    aq[c] = *(const u16x8*)&Qp[l31 * 64 + c * 16 + hi * 8];

  __syncthreads();  // S1: bias staged

  int rowq[16];
#pragma unroll
  for (int r = 0; r < 16; r++) rowq[r] = (r & 3) + 8 * (r >> 2) + 4 * hi;

  // -------- fused: scores = QK^T (pre-scaled), +bias, exp2, row-sum --------
  const u16* Kp = Kb + (size_t)bh * SS * HDD;
  f32x16 acc[8];
  float s16[16];
#pragma unroll
  for (int r = 0; r < 16; r++) s16[r] = 0.f;
#pragma unroll
  for (int kt = 0; kt < 8; kt++) {
    int kg = w * 256 + kt * 32;
    f32x16 a;
#pragma unroll
    for (int j = 0; j < 16; j++) a[j] = 0.f;
#pragma unroll
    for (int c = 0; c < 4; c++) {
      u16x8 kf = *(const u16x8*)&Kp[(size_t)(kg + l31) * 64 + c * 16 + hi * 8];
      a = mfma32(aq[c], kf, a);
    }
    int kgl = kg + l31;
#pragma unroll
    for (int r = 0; r < 16; r++) {
      float p = exp2f(a[r] + bias_lds[rowq[r] + 2047 - kgl]);
      a[r] = p;
      s16[r] += p;
    }
    acc[kt] = a;
  }
  // -------- cross-lane + cross-wave row sum --------
#pragma unroll
  for (int mask = 1; mask <= 16; mask <<= 1)
#pragma unroll
    for (int r = 0; r < 16; r++) s16[r] += __shfl_xor(s16[r], mask);
  if (l31 == 0) {
#pragma unroll
    for (int r = 0; r < 16; r++) red[w][rowq[r]] = s16[r];
  }
  __syncthreads();  // S2
  if (tid < 32) {
    float g = 0.f;
#pragma unroll
    for (int ww = 0; ww < 8; ww++) g += red[ww][tid];
    gval[tid] = g;
  }
  __syncthreads();  // S3
  float inv16[16];
#pragma unroll
  for (int r = 0; r < 16; r++) inv16[r] = 1.0f / gval[rowq[r]];

  // -------- normalize, store weights (nontemporal), PV --------
  float* wbase = wout + ((size_t)bh * SS + q0) * (size_t)SS;
  const u16* Vp = Vt + (size_t)bh * HDD * SS;
  f32x16 pv0, pv1;
#pragma unroll
  for (int j = 0; j < 16; j++) { pv0[j] = 0.f; pv1[j] = 0.f; }

#pragma unroll
  for (int kt = 0; kt < 8; kt++) {
    int kg = w * 256 + kt * 32;
#pragma unroll
    for (int r = 0; r < 16; r++) {
      float wv = acc[kt][r] * inv16[r];
      acc[kt][r] = wv;
      __builtin_nontemporal_store(wv, &wbase[(size_t)rowq[r] * SS + kg + l31]);
    }
#pragma unroll
    for (int r = 0; r < 16; r++)
      plds[w][rowq[r]][l31] = f2bf(acc[kt][r]);
#pragma unroll
    for (int kk = 0; kk < 32; kk += 16) {
      u16x8 pa  = *(const u16x8*)&plds[w][l31][kk + hi * 8];
      u16x8 vb0 = *(const u16x8*)&Vp[(size_t)l31 * SS + kg + kk + hi * 8];
      u16x8 vb1 = *(const u16x8*)&Vp[(size_t)(32 + l31) * SS + kg + kk + hi * 8];
      pv0 = mfma32(pa, vb0, pv0);
      pv1 = mfma32(pa, vb1, pv1);
    }
  }
  // -------- cross-wave PV reduction --------
  if (w >= 4) {
#pragma unroll
    for (int r = 0; r < 16; r++) {
      pvred[w - 4][rowq[r]][l31]      = pv0[r];
      pvred[w - 4][rowq[r]][32 + l31] = pv1[r];
    }
  }
  __syncthreads();  // S4
  if (w < 4) {
#pragma unroll
    for (int r = 0; r < 16; r++) {
      pvred[w][rowq[r]][l31]      += pv0[r];
      pvred[w][rowq[r]][32 + l31] += pv1[r];
    }
  }
  __syncthreads();  // S5
  int b = bh >> 4;
  for (int idx = tid; idx < 2048; idx += 512) {
    int qq = idx >> 6, hd = idx & 63;
    float sum = 0.f;
#pragma unroll
    for (int ww = 0; ww < 4; ww++) sum += pvred[ww][qq][hd];
    attn[((size_t)b * SS + q0 + qq) * DD + h * HDD + hd] = f2bf(sum);
  }
}

// ---------------- kernel 5: output projection GEMM (m97 structure) ---------
__global__ __launch_bounds__(256) void mhsa_gemm_out(
    const u16* __restrict__ A, const u16* __restrict__ Bm,
    const float* __restrict__ bo, float* __restrict__ out) {
  const int KD = DD;
  __shared__ __attribute__((aligned(16))) u16 lA[128 * 64];
  __shared__ __attribute__((aligned(16))) u16 lB[64 * 64];
  int tid = threadIdx.x;
  int bm = blockIdx.y, bn = blockIdx.x;
  int l = tid & 63, w = tid >> 6, wr = w >> 1, wc = w & 1;
  int l15 = l & 15, l4 = l >> 4;
  f32x4 acc[4][2];
#pragma unroll
  for (int mi = 0; mi < 4; mi++)
#pragma unroll
    for (int ni = 0; ni < 2; ni++)
#pragma unroll
      for (int j = 0; j < 4; j++) acc[mi][ni][j] = 0.f;

  const u16* Ag = A + (size_t)bm * 128 * KD;
  const u16* Bg = Bm + (size_t)bn * 64 * KD;
  const int srow = (l >> 3), scol = (l & 7) * 8;
  for (int kt = 0; kt < KD / 64; kt++) {
    const u16* As = Ag + (size_t)(w * 32 + srow) * KD + kt * 64 + scol;
    const u16* Bs = Bg + (size_t)(w * 16 + srow) * KD + kt * 64 + scol;
    u16* Ad = &lA[(w * 32) * 64];
    u16* Bd = &lB[(w * 16) * 64];
#pragma unroll
    for (int t = 0; t < 4; t++)
      gload16(As + (size_t)t * 8 * KD, Ad + t * 8 * 64);
#pragma unroll
    for (int t = 0; t < 2; t++)
      gload16(Bs + (size_t)t * 8 * KD, Bd + t * 8 * 64);
    __syncthreads();
#pragma unroll
    for (int kk = 0; kk < 64; kk += 32) {
      u16x8 af[4], bf[2];
#pragma unroll
      for (int mi = 0; mi < 4; mi++)
        af[mi] = *(const u16x8*)&lA[(wr * 64 + mi * 16 + l15) * 64 + kk + l4 * 8];
#pragma unroll
      for (int ni = 0; ni < 2; ni++)
        bf[ni] = *(const u16x8*)&lB[(wc * 32 + ni * 16 + l15) * 64 + kk + l4 * 8];
#pragma unroll
      for (int mi = 0; mi < 4; mi++)
#pragma unroll
        for (int ni = 0; ni < 2; ni++)
          acc[mi][ni] = mfma16(af[mi], bf[ni], acc[mi][ni]);
    }
    __syncthreads();
  }
  int rowbase = bm * 128 + wr * 64;
  int colbase = bn * 64 + wc * 32;
#pragma unroll
  for (int ni = 0; ni < 2; ni++) {
    int col = colbase + ni * 16 + l15;
    float bias = bo[col];
#pragma unroll
    for (int mi = 0; mi < 4; mi++) {
#pragma unroll
      for (int j = 0; j < 4; j++) {
        int row = rowbase + mi * 16 + l4 * 4 + j;
        out[(size_t)row * DD + col] = acc[mi][ni][j] + bias;
      }
    }
  }
}

// ---------------- launcher -------------------------------------------------
extern "C" void kernel_launch(void* const* d_in, const int* in_sizes, int n_in,
                              void* d_out, int out_size, void* d_ws, size_t ws_size,
                              hipStream_t stream) {
  const float* x  = (const float*)d_in[0];
  const float* Wq = (const float*)d_in[1];
  const float* bq = (const float*)d_in[2];
  const float* Wk = (const float*)d_in[3];
  const float* bk = (const float*)d_in[4];
  const float* Wv = (const float*)d_in[5];
  const float* bv = (const float*)d_in[6];
  const float* Wo = (const float*)d_in[7];
  const float* bo = (const float*)d_in[8];
  const float* rb = (const float*)d_in[9];

  char* ws = (char*)d_ws;
  u16* xb    = (u16*)(ws + 0);           //  8 MiB  (4096x1024)
  u16* wpack = (u16*)(ws + 8388608);     //  6 MiB  (3072x1024)
  u16* wob   = (u16*)(ws + 14680064);    //  2 MiB  (1024x1024)
  u16* Qb    = (u16*)(ws + 16777216);    //  8 MiB  [b,h,s,hd] (pre-scaled)
  u16* Kb    = (u16*)(ws + 25165824);    //  8 MiB
  u16* Vb    = (u16*)(ws + 33554432);    //  8 MiB
  u16* Vt    = (u16*)(ws + 41943040);    //  8 MiB  [b,h,hd,s]
  u16* attnb = (u16*)(ws + 50331648);    //  8 MiB  [b,s,h*hd]
  if (ws_size < 58720256) return;

  float* out   = (float*)d_out;
  float* wout  = out + (size_t)BB * SS * DD;  // weights region

  mhsa_convert<<<2048, 256, 0, stream>>>(x, Wq, Wk, Wv, Wo, xb, wpack, wob);
  mhsa_gemm_qkv<<<dim3(24, 32), 256, 0, stream>>>(xb, wpack, bq, bk, bv, Qb, Kb, Vb);
  mhsa_transpose_v<<<dim3(32, 32), 256, 0, stream>>>(Vb, Vt);
  mhsa_attn<<<dim3(64, 32), 512, 0, stream>>>(Qb, Kb, Vt, rb, wout, attnb);
  mhsa_gemm_out<<<dim3(16, 32), 256, 0, stream>>>(attnb, wob, bo, out);
}